// Round 7
// baseline (33.603 us; speedup 1.0000x reference)
//
#include <hip/hip_runtime.h>
#include <hip/hip_bf16.h>
#include <math.h>

// Problem constants (fixed by setup_inputs)
constexpr int B_ = 16, S_ = 512, T_ = 4096, E_ = 256;

typedef __attribute__((ext_vector_type(8))) short short8;
typedef __attribute__((ext_vector_type(4))) float f32x4;

// Workspace layout (bytes)
constexpr size_t FLAGS_OFF = 0;             // 32 ints
constexpr size_t WT_OFF    = 4096;          // 256x256 bf16 W^T = 128KB

// -ln(10000)/256
#define NEGC (-0.035977892f)

__device__ __forceinline__ unsigned pk_bf16(float a, float b) {
    __hip_bfloat162 h = __float22bfloat162_rn(make_float2(a, b));
    return *(unsigned*)&h;
}
__device__ __forceinline__ short bf16s(float x) {
    unsigned u = __float_as_uint(x);
    u += 0x7FFFu + ((u >> 16) & 1u);
    return (short)(u >> 16);
}

// ---------------------------------------------------------------------------
// Prep: [0,32) aligner-recurrence validation (8 ids/thread, int4) -> flags;
//       [32,48) W^T -> bf16 wt.  (R5-proven)
__global__ __launch_bounds__(256) void k_prep(
    const int* __restrict__ align, const int* __restrict__ text,
    const float* __restrict__ W,
    int* __restrict__ flags, short* __restrict__ wt)
{
    const int bid = blockIdx.x, tid = threadIdx.x;
    if (bid < 32) {
        __shared__ int f;
        if (tid == 0) f = 0;
        __syncthreads();
        const int base = (bid * 256 + tid) * 8;
        const int4 a0 = *(const int4*)(align + base);
        const int4 a1 = *(const int4*)(align + base + 4);
        const int av[8] = {a0.x, a0.y, a0.z, a0.w, a1.x, a1.y, a1.z, a1.w};
        int bad = 0;
#pragma unroll
        for (int m = 0; m < 8; ++m) {
            const int id = base + m;
            const int t = id & (T_ - 1), b = id >> 12;
            if (t > 0) {
                const int prev = (t - 1) >> 3;
                const int expct = (av[m] == text[b * S_ + prev]) ? prev : min(prev + 1, S_ - 1);
                if ((t >> 3) != expct) bad = 1;
            }
        }
        if (bad) f = 1;                  // benign race: all writers store 1
        __syncthreads();
        if (tid == 0) flags[bid] = f;
    } else {
        const int kb = (bid - 32) * 16;
        short8 v0, v1;
#pragma unroll
        for (int j = 0; j < 8; ++j) v0[j] = bf16s(W[(kb + j) * E_ + tid]);
#pragma unroll
        for (int j = 0; j < 8; ++j) v1[j] = bf16s(W[(kb + 8 + j) * E_ + tid]);
        *(short8*)(wt + tid * E_ + kb)     = v0;
        *(short8*)(wt + tid * E_ + kb + 8) = v1;
    }
}

// ---------------------------------------------------------------------------
// Fused GEMM. Block = 1 phone x 16 batches x 64 N-cols; grid (512, 4) = 2048
// blocks at 3 blocks/CU -> ~2.7 generations so staging of gen g+1 overlaps the
// store drain of gen g. Tail is per-wave (no block barrier after phase 2).
__global__ __launch_bounds__(256) void k_fused(
    const float* __restrict__ enc, const short* __restrict__ wt,
    const float* __restrict__ bpos,
    const float* __restrict__ pitch, const int* __restrict__ beats,
    const float* __restrict__ wpitch, const float* __restrict__ bpitch,
    const float* __restrict__ embb,
    const float* __restrict__ W, const int* __restrict__ align,
    const int* __restrict__ text, const int* __restrict__ flags,
    float* __restrict__ out)
{
    __shared__ __align__(16) short Bs[64 * 256];   // 32KB   W^T slice [n][k]
    __shared__ __align__(16) short As[16 * 256];   // 8KB    PE rows, then enc rows
    __shared__ float pl[16 * 68];                  // 4.25KB PEW slice (rows 0-7 valid)
    __shared__ float tr[4][16][20];                // 5KB    per-wave acc transpose

    const int tid = threadIdx.x;
    const int i0 = blockIdx.x;                     // phone index 0..511
    const int n0 = blockIdx.y * 64;
    const int t0 = i0 * 8;                         // 8 output frames of this phone

    // ---- fallback flag (never set for this data) ----
    const bool fb = __any(flags[tid & 31] != 0);
    if (fb) {
        // exact fp32 slow path for this block's tile (slow, never taken)
        int (*idxl)[8] = (int(*)[8])As;
        if (tid < 16) {
            int i = 0;
            const int b = tid;
            if (i0 == 0) idxl[b][0] = 0;
            for (int t = 1; t < t0 + 8; ++t) {
                if (align[b * T_ + t] != text[b * S_ + i]) i = min(i + 1, S_ - 1);
                if (t >= t0) idxl[b][t - t0] = i;
            }
        }
        __syncthreads();
        const int r = tid >> 1, half = tid & 1;    // r < 128 = 16b x 8t
        const int bq = r >> 3, d = r & 7;
        const int t = t0 + d;
        const int i = idxl[bq][d];
        const float* erow = enc + (size_t)(bq * S_ + i) * E_;
        const float p = pitch[(size_t)bq * T_ + t];
        const int bt = beats[(size_t)bq * T_ + t];
        for (int cc = 0; cc < 32; ++cc) {
            const int col = n0 + half * 32 + cc;
            float acc = 0.f;
            for (int k2 = 0; k2 < 128; ++k2) {
                const float dd = __expf((float)(2 * k2) * NEGC);
                float s, c;
                __sincosf((float)t * dd, &s, &c);
                acc += (erow[2 * k2] + s) * W[(2 * k2) * E_ + col]
                     + (erow[2 * k2 + 1] + c) * W[(2 * k2 + 1) * E_ + col];
            }
            out[((size_t)bq * T_ + t) * E_ + col] =
                erow[col] + acc + bpos[col] + p * wpitch[col] + bpitch[col]
                + (bt ? embb[E_ + col] : embb[col]);
        }
        return;
    }

    // ---- stage Bs: wt rows n0..n0+64 (vector, swizzled; R5-proven) ----
    {
        const int r = tid >> 2, c4 = tid & 3;
        const short* bp = wt + (size_t)(n0 + r) * E_;
#pragma unroll
        for (int jj = 0; jj < 8; ++jj) {
            const int seg = c4 + 4 * jj;
            short8 v = *(const short8*)(bp + seg * 8);
            *(short8*)&Bs[(r * 256 + seg * 8) ^ ((r & 7) << 3)] = v;
        }
    }
    // ---- stage As = PE rows 0..7 (on-the-fly sincos; threads 0-127) ----
    if (tid < 128) {
        const int r = tid >> 4, c16 = tid & 15;
        const float tf = (float)(t0 + r);
#pragma unroll
        for (int g = 0; g < 2; ++g) {
            const int k0 = c16 * 16 + g * 8;
            union { short8 v; unsigned u[4]; } cv;
#pragma unroll
            for (int m = 0; m < 4; ++m) {
                const int j2 = c16 * 8 + g * 4 + m;
                const float d = __expf((float)(2 * j2) * NEGC);
                float s, c;
                __sincosf(tf * d, &s, &c);
                cv.u[m] = pk_bf16(s, c);
            }
            *(short8*)&As[(r * 256 + k0) ^ ((r & 7) << 3)] = cv.v;
        }
    }
    __syncthreads();

    const int wid = tid >> 6, lane = tid & 63;
    const int q = lane >> 4, c = lane & 15;
    const int rb = wid * 16 + c;                   // wave owns n-quarter [16w,16w+16)

    // ---- phase 1 MFMA: PEW slice (t-rows 0-7 valid; rows 8-15 garbage, unread) ----
    {
        f32x4 p = {0.f, 0.f, 0.f, 0.f};
#pragma unroll
        for (int ks = 0; ks < 8; ++ks) {
            const int kidx = ks * 32 + q * 8;
            short8 a = *(const short8*)&As[(c * 256 + kidx) ^ ((c & 7) << 3)];
            short8 b = *(const short8*)&Bs[(rb * 256 + kidx) ^ ((rb & 7) << 3)];
            p = __builtin_amdgcn_mfma_f32_16x16x32_bf16(a, b, p, 0, 0, 0);
        }
#pragma unroll
        for (int rr = 0; rr < 4; ++rr)
            pl[(q * 4 + rr) * 68 + wid * 16 + c] = p[rr];
    }
    __syncthreads();   // As(PE) reads done; pl visible

    // ---- stage As = enc rows (row r = batch r, phone i0); contiguous 64B/lane ----
    {
        const int r = tid >> 4, c16 = tid & 15;
        const float* ap = enc + (size_t)(r * S_ + i0) * E_ + c16 * 16;
        const float4 e0 = *(const float4*)(ap);
        const float4 e1 = *(const float4*)(ap + 4);
        const float4 e2 = *(const float4*)(ap + 8);
        const float4 e3 = *(const float4*)(ap + 12);
        union { short8 v; unsigned u[4]; } cv0, cv1;
        cv0.u[0] = pk_bf16(e0.x, e0.y); cv0.u[1] = pk_bf16(e0.z, e0.w);
        cv0.u[2] = pk_bf16(e1.x, e1.y); cv0.u[3] = pk_bf16(e1.z, e1.w);
        cv1.u[0] = pk_bf16(e2.x, e2.y); cv1.u[1] = pk_bf16(e2.z, e2.w);
        cv1.u[2] = pk_bf16(e3.x, e3.y); cv1.u[3] = pk_bf16(e3.z, e3.w);
        *(short8*)&As[(r * 256 + c16 * 16)     ^ ((r & 7) << 3)] = cv0.v;
        *(short8*)&As[(r * 256 + c16 * 16 + 8) ^ ((r & 7) << 3)] = cv1.v;
    }
    __syncthreads();   // last block-wide barrier

    // ---- phase 2 MFMA: 16 batches x wave's 16 cols ----
    f32x4 acc = {0.f, 0.f, 0.f, 0.f};
#pragma unroll
    for (int ks = 0; ks < 8; ++ks) {
        const int kidx = ks * 32 + q * 8;
        short8 a = *(const short8*)&As[(c * 256 + kidx) ^ ((c & 7) << 3)];
        short8 b = *(const short8*)&Bs[(rb * 256 + kidx) ^ ((rb & 7) << 3)];
        acc = __builtin_amdgcn_mfma_f32_16x16x32_bf16(a, b, acc, 0, 0, 0);
    }

    // ---- per-wave transpose (D: row = 4q+rr = batch, col = c = n-in-quarter) ----
#pragma unroll
    for (int rr = 0; rr < 4; ++rr)
        tr[wid][q * 4 + rr][c] = acc[rr];
    asm volatile("s_waitcnt lgkmcnt(0)" ::: "memory");   // wave-local visibility
    __builtin_amdgcn_sched_barrier(0);

    // ---- per-wave epilogue: lane = (batch r_l, col-chunk cq); 8 stores ----
    const int r_l = lane >> 2, cq = lane & 3;
    const int gc = n0 + wid * 16 + cq * 4;
    const size_t prow = (size_t)r_l * T_ + t0;

    const float4 pi0 = *(const float4*)(pitch + prow);
    const float4 pi1 = *(const float4*)(pitch + prow + 4);
    const int4   bt0 = *(const int4*)(beats + prow);
    const int4   bt1 = *(const int4*)(beats + prow + 4);
    const f32x4  e4  = *(const f32x4*)(enc + (size_t)(r_l * S_ + i0) * E_ + gc);
    const f32x4  trv = *(const f32x4*)&tr[wid][r_l][cq * 4];
    const f32x4  wp4 = *(const f32x4*)(wpitch + gc);
    const f32x4  cst = *(const f32x4*)(bpitch + gc) + *(const f32x4*)(bpos + gc);
    const f32x4  be0 = *(const f32x4*)(embb + gc);
    const f32x4  be1 = *(const f32x4*)(embb + E_ + gc);

    const f32x4 base = trv + e4 + cst;
    const float pp[8] = {pi0.x, pi0.y, pi0.z, pi0.w, pi1.x, pi1.y, pi1.z, pi1.w};
    const int   bb[8] = {bt0.x, bt0.y, bt0.z, bt0.w, bt1.x, bt1.y, bt1.z, bt1.w};
#pragma unroll
    for (int d = 0; d < 8; ++d) {
        const f32x4 pv = *(const f32x4*)&pl[d * 68 + wid * 16 + cq * 4];  // broadcast read
        const f32x4 be = bb[d] ? be1 : be0;
        f32x4 o = base + pv + pp[d] * wp4 + be;
        __builtin_nontemporal_store(o, (f32x4*)(out + (prow + d) * E_ + gc));
    }
}

// ---------------------------------------------------------------------------
extern "C" void kernel_launch(void* const* d_in, const int* in_sizes, int n_in,
                              void* d_out, int out_size, void* d_ws, size_t ws_size,
                              hipStream_t stream) {
    const float* enc    = (const float*)d_in[0];
    const int*   align  = (const int*)  d_in[1];
    const int*   text   = (const int*)  d_in[2];
    const float* pitch  = (const float*)d_in[3];
    const int*   beats  = (const int*)  d_in[4];
    const float* wpitch = (const float*)d_in[5];
    const float* bpitch = (const float*)d_in[6];
    const float* embb   = (const float*)d_in[7];
    const float* wpos   = (const float*)d_in[8];
    const float* bpos   = (const float*)d_in[9];
    float* out = (float*)d_out;

    char* ws = (char*)d_ws;
    int*   flags = (int*)  (ws + FLAGS_OFF);
    short* wt    = (short*)(ws + WT_OFF);

    hipLaunchKernelGGL(k_prep, dim3(48), dim3(256), 0, stream,
                       align, text, wpos, flags, wt);
    hipLaunchKernelGGL(k_fused, dim3(512, 4), dim3(256), 0, stream,
                       enc, wt, bpos, pitch, beats, wpitch, bpitch, embb,
                       wpos, align, text, flags, out);
}

// Round 8
// 25.579 us; speedup vs baseline: 1.3137x; 1.3137x over previous
//
#include <hip/hip_runtime.h>
#include <hip/hip_bf16.h>
#include <math.h>

// Problem constants (fixed by setup_inputs)
constexpr int B_ = 16, S_ = 512, T_ = 4096, E_ = 256;

typedef __attribute__((ext_vector_type(8))) short short8;
typedef __attribute__((ext_vector_type(4))) float f32x4;

// Workspace layout (bytes)
constexpr size_t FLAGS_OFF = 0;             // 32 ints
constexpr size_t WT_OFF    = 4096;          // 256x256 bf16 W^T = 128KB

// -ln(10000)/256
#define NEGC (-0.035977892f)

__device__ __forceinline__ unsigned pk_bf16(float a, float b) {
    __hip_bfloat162 h = __float22bfloat162_rn(make_float2(a, b));
    return *(unsigned*)&h;
}
__device__ __forceinline__ short bf16s(float x) {
    unsigned u = __float_as_uint(x);
    u += 0x7FFFu + ((u >> 16) & 1u);
    return (short)(u >> 16);
}

// ---------------------------------------------------------------------------
// Prep: [0,32) aligner-recurrence validation (8 ids/thread, int4) -> flags;
//       [32,48) W^T -> bf16 wt.  (R5-proven, unchanged)
__global__ __launch_bounds__(256) void k_prep(
    const int* __restrict__ align, const int* __restrict__ text,
    const float* __restrict__ W,
    int* __restrict__ flags, short* __restrict__ wt)
{
    const int bid = blockIdx.x, tid = threadIdx.x;
    if (bid < 32) {
        __shared__ int f;
        if (tid == 0) f = 0;
        __syncthreads();
        const int base = (bid * 256 + tid) * 8;
        const int4 a0 = *(const int4*)(align + base);
        const int4 a1 = *(const int4*)(align + base + 4);
        const int av[8] = {a0.x, a0.y, a0.z, a0.w, a1.x, a1.y, a1.z, a1.w};
        int bad = 0;
#pragma unroll
        for (int m = 0; m < 8; ++m) {
            const int id = base + m;
            const int t = id & (T_ - 1), b = id >> 12;
            if (t > 0) {
                const int prev = (t - 1) >> 3;
                const int expct = (av[m] == text[b * S_ + prev]) ? prev : min(prev + 1, S_ - 1);
                if ((t >> 3) != expct) bad = 1;
            }
        }
        if (bad) f = 1;                  // benign race: all writers store 1
        __syncthreads();
        if (tid == 0) flags[bid] = f;
    } else {
        const int kb = (bid - 32) * 16;
        short8 v0, v1;
#pragma unroll
        for (int j = 0; j < 8; ++j) v0[j] = bf16s(W[(kb + j) * E_ + tid]);
#pragma unroll
        for (int j = 0; j < 8; ++j) v1[j] = bf16s(W[(kb + 8 + j) * E_ + tid]);
        *(short8*)(wt + tid * E_ + kb)     = v0;
        *(short8*)(wt + tid * E_ + kb + 8) = v1;
    }
}

// ---------------------------------------------------------------------------
// Fused GEMM, R5 structure at half N-tile: block = 4 phones x 16 batches x
// 32 N-cols; grid (128, 8) = 1024 blocks; LDS 53,248B -> 3 blocks/CU (vs R5's
// 2) so block phases drift and store drains overlap other blocks' compute.
__global__ __launch_bounds__(256, 3) void k_fused(
    const float* __restrict__ enc, const short* __restrict__ wt,
    const float* __restrict__ bpos,
    const float* __restrict__ pitch, const int* __restrict__ beats,
    const float* __restrict__ wpitch, const float* __restrict__ bpitch,
    const float* __restrict__ embb,
    const float* __restrict__ W, const int* __restrict__ align,
    const int* __restrict__ text, const int* __restrict__ flags,
    float* __restrict__ out)
{
    __shared__ __align__(16) short As[64 * 256];   // 32KB: PE rows 0-31 -> enc 0-63 -> ew f32[64][36]
    __shared__ __align__(16) short Bs[32 * 256];   // 16KB  W^T slice [n][k]
    __shared__ float pl[4 * 256];                  // 4KB   PEW patches [tq*2+nq][16][16]

    const int tid = threadIdx.x;
    const int i0 = blockIdx.x * 4;                 // phone base
    const int n0 = blockIdx.y * 32;
    const int t0base = i0 * 8;

    // ---- fallback flag (never set for this data) ----
    const bool fb = __any(flags[tid & 31] != 0);
    if (fb) {
        // exact fp32 slow path (never taken). idxl aliases As.
        int (*idxl)[32] = (int(*)[32])As;
        if (tid < 16) {
            int i = 0;
            const int b = tid;
            if (i0 == 0) idxl[b][0] = 0;
            for (int t = 1; t < t0base + 32; ++t) {
                if (align[b * T_ + t] != text[b * S_ + i]) i = min(i + 1, S_ - 1);
                if (t >= t0base) idxl[b][t - t0base] = i;
            }
        }
        __syncthreads();
#pragma unroll
        for (int rr = 0; rr < 2; ++rr) {
            const int r = tid * 2 + rr;            // 0..511 = 16b x 32t
            const int bq = r >> 5, tt = r & 31;
            const int t = t0base + tt;
            const int i = idxl[bq][tt];
            const float* erow = enc + (size_t)(bq * S_ + i) * E_;
            const float p = pitch[(size_t)bq * T_ + t];
            const int bt = beats[(size_t)bq * T_ + t];
            for (int cc = 0; cc < 32; ++cc) {
                const int col = n0 + cc;
                float acc = 0.f;
                for (int k2 = 0; k2 < 128; ++k2) {
                    const float dd = __expf((float)(2 * k2) * NEGC);
                    float s, c;
                    __sincosf((float)t * dd, &s, &c);
                    acc += (erow[2 * k2] + s) * W[(2 * k2) * E_ + col]
                         + (erow[2 * k2 + 1] + c) * W[(2 * k2 + 1) * E_ + col];
                }
                out[((size_t)bq * T_ + t) * E_ + col] =
                    erow[col] + acc + bpos[col] + p * wpitch[col] + bpitch[col]
                    + (bt ? embb[E_ + col] : embb[col]);
            }
        }
        return;
    }

    // ---- stage Bs: wt rows n0..n0+32 (vector, swizzled) ----
    {
        const int r = tid >> 3, c8 = tid & 7;
        const short* bp = wt + (size_t)(n0 + r) * E_;
#pragma unroll
        for (int jj = 0; jj < 4; ++jj) {
            const int seg = c8 + 8 * jj;
            short8 v = *(const short8*)(bp + seg * 8);
            *(short8*)&Bs[(r * 256 + seg * 8) ^ ((r & 7) << 3)] = v;
        }
    }
    // ---- stage As = PE rows 0..31 (on-the-fly sincos; R5-proven pattern) ----
    {
        const int r = tid >> 3, c8 = tid & 7;
        const float tf = (float)(t0base + r);
#pragma unroll
        for (int jj = 0; jj < 4; ++jj) {
            const int seg = c8 * 4 + jj;
            union { short8 v; unsigned u[4]; } cv;
#pragma unroll
            for (int m = 0; m < 4; ++m) {
                const int j2 = seg * 4 + m;
                const float d = __expf((float)(2 * j2) * NEGC);
                float s, c;
                __sincosf(tf * d, &s, &c);
                cv.u[m] = pk_bf16(s, c);
            }
            *(short8*)&As[(r * 256 + seg * 8) ^ ((r & 7) << 3)] = cv.v;
        }
    }
    __syncthreads();

    const int wid = tid >> 6, lane = tid & 63;
    const int q = lane >> 4, c = lane & 15;

    // ---- phase 1 MFMA: 32x32 PEW slice, wave (tq, nq) = 16t x 16n, no waste ----
    {
        const int tq = wid >> 1, nqp = wid & 1;
        const int ar = tq * 16 + c;
        const int br = nqp * 16 + c;
        f32x4 p = {0.f, 0.f, 0.f, 0.f};
#pragma unroll
        for (int ks = 0; ks < 8; ++ks) {
            const int kidx = ks * 32 + q * 8;
            short8 a = *(const short8*)&As[(ar * 256 + kidx) ^ ((ar & 7) << 3)];
            short8 b = *(const short8*)&Bs[(br * 256 + kidx) ^ ((br & 7) << 3)];
            p = __builtin_amdgcn_mfma_f32_16x16x32_bf16(a, b, p, 0, 0, 0);
        }
#pragma unroll
        for (int rr = 0; rr < 4; ++rr)
            pl[(tq * 2 + nqp) * 256 + (q * 4 + rr) * 16 + c] = p[rr];
    }
    __syncthreads();   // As(PE) reads done; pl visible

    // ---- stage As = enc rows 0..63 (row r: b = r>>2, phone = i0 + (r&3)) ----
    {
        const int r = tid >> 2, c4 = tid & 3;
        const float* ap = enc + (size_t)((r >> 2) * S_ + i0 + (r & 3)) * E_;
#pragma unroll
        for (int jj = 0; jj < 8; ++jj) {
            const int seg = c4 + 4 * jj;
            float4 f0 = *(const float4*)(ap + seg * 8);
            float4 f1 = *(const float4*)(ap + seg * 8 + 4);
            union { short8 v; unsigned u[4]; } cv;
            cv.u[0] = pk_bf16(f0.x, f0.y);
            cv.u[1] = pk_bf16(f0.z, f0.w);
            cv.u[2] = pk_bf16(f1.x, f1.y);
            cv.u[3] = pk_bf16(f1.z, f1.w);
            *(short8*)&As[(r * 256 + seg * 8) ^ ((r & 7) << 3)] = cv.v;
        }
    }
    __syncthreads();

    // ---- phase 2 MFMA: wave (mq, nq) = 32 enc-rows x 16 cols, 16 MFMA ----
    const int mq = wid >> 1, nq = wid & 1;
    const int ra0 = mq * 32 + c, ra1 = ra0 + 16;
    const int rb = nq * 16 + c;
    f32x4 acc0 = {0.f, 0.f, 0.f, 0.f}, acc1 = {0.f, 0.f, 0.f, 0.f};
#pragma unroll
    for (int ks = 0; ks < 8; ++ks) {
        const int kidx = ks * 32 + q * 8;
        short8 a0 = *(const short8*)&As[(ra0 * 256 + kidx) ^ ((ra0 & 7) << 3)];
        short8 a1 = *(const short8*)&As[(ra1 * 256 + kidx) ^ ((ra1 & 7) << 3)];
        short8 b  = *(const short8*)&Bs[(rb * 256 + kidx) ^ ((rb & 7) << 3)];
        acc0 = __builtin_amdgcn_mfma_f32_16x16x32_bf16(a0, b, acc0, 0, 0, 0);
        acc1 = __builtin_amdgcn_mfma_f32_16x16x32_bf16(a1, b, acc1, 0, 0, 0);
    }

    // ---- pre-reads (pl stable since bar2; overlaps other waves' phase 2) ----
    const int c8q = tid & 7, rgrp = tid >> 3;      // tail: col-chunk, row-group
    const int j = rgrp & 3;                        // phone offset (same for both p)
    const int gc = n0 + 4 * c8q;
    f32x4 pv[8];
#pragma unroll
    for (int d = 0; d < 8; ++d) {
        const int tl = j * 8 + d;
        pv[d] = *(const f32x4*)&pl[((tl >> 4) * 2 + (c8q >> 2)) * 256
                                   + (tl & 15) * 16 + ((4 * c8q) & 15)];
    }
    const f32x4 wp4 = *(const f32x4*)(wpitch + gc);
    const f32x4 cst = *(const f32x4*)(bpitch + gc) + *(const f32x4*)(bpos + gc);
    const f32x4 be0 = *(const f32x4*)(embb + gc);
    const f32x4 be1 = *(const f32x4*)(embb + E_ + gc);
    __syncthreads();   // all As(enc) reads done -> reuse As as ew

    // ---- transpose acc through LDS (D: row = 4q+rr, col = c); stride 36 ----
    float* ew = (float*)As;                        // [64][36], 16B-aligned rows
#pragma unroll
    for (int rr = 0; rr < 4; ++rr) {
        ew[(mq * 32 + q * 4 + rr) * 36 + nq * 16 + c]      = acc0[rr];
        ew[(mq * 32 + 16 + q * 4 + rr) * 36 + nq * 16 + c] = acc1[rr];
    }
    __syncthreads();   // ew visible

    // ---- epilogue: lane = (rgrp, c8q); 2 row-passes x 8 frames ----
#pragma unroll
    for (int p = 0; p < 2; ++p) {
        const int row = rgrp + 32 * p;
        const int bq = row >> 2;
        const size_t prow = (size_t)bq * T_ + t0base + j * 8;
        const float4 pi0 = *(const float4*)(pitch + prow);
        const float4 pi1 = *(const float4*)(pitch + prow + 4);
        const int4  bt0 = *(const int4*)(beats + prow);
        const int4  bt1 = *(const int4*)(beats + prow + 4);
        const f32x4 e4  = *(const f32x4*)(enc + (size_t)(bq * S_ + i0 + j) * E_ + gc);
        const f32x4 ewv = *(const f32x4*)&ew[row * 36 + 4 * c8q];
        const f32x4 base = ewv + e4 + cst;
        const float pp[8] = {pi0.x, pi0.y, pi0.z, pi0.w, pi1.x, pi1.y, pi1.z, pi1.w};
        const int   bb[8] = {bt0.x, bt0.y, bt0.z, bt0.w, bt1.x, bt1.y, bt1.z, bt1.w};
#pragma unroll
        for (int d = 0; d < 8; ++d) {
            const f32x4 be = bb[d] ? be1 : be0;
            f32x4 o = base + pv[d] + pp[d] * wp4 + be;
            __builtin_nontemporal_store(o, (f32x4*)(out + (prow + d) * E_ + gc));
        }
    }
}

// ---------------------------------------------------------------------------
extern "C" void kernel_launch(void* const* d_in, const int* in_sizes, int n_in,
                              void* d_out, int out_size, void* d_ws, size_t ws_size,
                              hipStream_t stream) {
    const float* enc    = (const float*)d_in[0];
    const int*   align  = (const int*)  d_in[1];
    const int*   text   = (const int*)  d_in[2];
    const float* pitch  = (const float*)d_in[3];
    const int*   beats  = (const int*)  d_in[4];
    const float* wpitch = (const float*)d_in[5];
    const float* bpitch = (const float*)d_in[6];
    const float* embb   = (const float*)d_in[7];
    const float* wpos   = (const float*)d_in[8];
    const float* bpos   = (const float*)d_in[9];
    float* out = (float*)d_out;

    char* ws = (char*)d_ws;
    int*   flags = (int*)  (ws + FLAGS_OFF);
    short* wt    = (short*)(ws + WT_OFF);

    hipLaunchKernelGGL(k_prep, dim3(48), dim3(256), 0, stream,
                       align, text, wpos, flags, wt);
    hipLaunchKernelGGL(k_fused, dim3(S_ / 4, 8), dim3(256), 0, stream,
                       enc, wt, bpos, pitch, beats, wpitch, bpitch, embb,
                       wpos, align, text, flags, out);
}